// Round 9
// baseline (2087.724 us; speedup 1.0000x reference)
//
#include <hip/hip_runtime.h>
#include <cmath>

// Problem geometry (fixed by setup_inputs)
#define HH 160
#define WW 192
#define DD 160
#define WD (WW*DD)          // 30720
#define NPTS (HH*WW*DD)     // 4,915,200
#define NP4  (NPTS/4)
#define INV_WSZ (1.0f/729.0f)
#define ADAM_B1 0.9f
#define ADAM_B2 0.999f
#define ADAM_LR 0.1f
#define ADAM_EPS 1e-8f
#define NBLK_FINAL 3840     // HH*WW/8 grad_adam blocks

// ---------------- persistent device-global scratch (~460 MB) ----------------
__device__ __align__(16) float g_flowA[3*NPTS];
__device__ __align__(16) float g_flowB[3*NPTS];
__device__ __align__(16) float g_m   [3*NPTS];
__device__ __align__(16) float g_v   [3*NPTS];
__device__ __align__(16) float g_vh  [3*NPTS];
__device__ __align__(16) float g_X   [3*NPTS];
__device__ __align__(16) float g_Y   [3*NPTS];
__device__ __align__(16) float g_I   [NPTS];     // trilinear value at fin
__device__ __align__(16) float g_G   [3*NPTS];   // trilinear coord-gradients at fin
__device__ __align__(16) float g_uJ  [NPTS];
__device__ __align__(16) float g_Jv  [NPTS];
__device__ double g_part[8192];

// ---------------- helpers ----------------

typedef float nat4 __attribute__((ext_vector_type(4)));  // native clang vector for NT builtins

__device__ __forceinline__ float4 ld4(const float* p) { return *reinterpret_cast<const float4*>(p); }
__device__ __forceinline__ void  st4(float* p, float4 v) { *reinterpret_cast<float4*>(p) = v; }
__device__ __forceinline__ float4 ld4nt(const float* p) {
    nat4 t = __builtin_nontemporal_load(reinterpret_cast<const nat4*>(p));
    return float4{t.x, t.y, t.z, t.w};
}
__device__ __forceinline__ void st4nt(float* p, float4 v) {
    nat4 t = {v.x, v.y, v.z, v.w};
    __builtin_nontemporal_store(t, reinterpret_cast<nat4*>(p));
}
#define UNPK(V,A) { A[0]=(V).x; A[1]=(V).y; A[2]=(V).z; A[3]=(V).w; }

__device__ __forceinline__ float fetchx(const float* __restrict__ x, int i, int j, int k) {
    if ((unsigned)i >= (unsigned)HH || (unsigned)j >= (unsigned)WW || (unsigned)k >= (unsigned)DD)
        return 0.0f;
    return x[(i*WW + j)*DD + k];
}

// ====== k1: fused warp + trilinear gradients + D-axis box of (I, I^2, I*J) ======
__global__ void __launch_bounds__(320) warp_momD_k(
        const float* __restrict__ x, const float* __restrict__ y,
        const float* __restrict__ finit, int fin_code)
{
    __shared__ __align__(16) float sI[8][168];   // 4 zero-pad front/back
    __shared__ __align__(16) float sJ[8][168];
    int tx = threadIdx.x;                 // 0..39
    int ty = threadIdx.y;                 // 0..7
    int line = blockIdx.x*8 + ty;         // h*WW + w
    int h = line / WW, w = line % WW;
    int dp = tx*4;
    int idx = line*DD + dp;
    const float* fin = (fin_code == 0) ? finit : ((fin_code == 1) ? g_flowA : g_flowB);

    float F0[4], F1[4], F2[4], Y4[4];
    { float4 a = ld4(fin + idx);          UNPK(a, F0); }
    { float4 a = ld4(fin + NPTS + idx);   UNPK(a, F1); }
    { float4 a = ld4(fin + 2*NPTS + idx); UNPK(a, F2); }
    { float4 a = ld4(y + idx);            UNPK(a, Y4); }

    float GX[4], GY[4], GZ[4], IV[4];
#pragma unroll
    for (int e = 0; e < 4; e++) {
        float c0 = (float)h + F0[e];
        float c1 = (float)w + F1[e];
        float c2 = (float)(dp + e) + F2[e];
        float fl0 = floorf(c0), fl1 = floorf(c1), fl2 = floorf(c2);
        int i0 = (int)fl0, j0 = (int)fl1, k0 = (int)fl2;
        float fx = c0 - fl0, fy = c1 - fl1, fz = c2 - fl2;
        float v000 = fetchx(x, i0,   j0,   k0  ), v001 = fetchx(x, i0,   j0,   k0+1);
        float v010 = fetchx(x, i0,   j0+1, k0  ), v011 = fetchx(x, i0,   j0+1, k0+1);
        float v100 = fetchx(x, i0+1, j0,   k0  ), v101 = fetchx(x, i0+1, j0,   k0+1);
        float v110 = fetchx(x, i0+1, j0+1, k0  ), v111 = fetchx(x, i0+1, j0+1, k0+1);
        float c00 = v000*(1.0f-fz) + v001*fz;
        float c01 = v010*(1.0f-fz) + v011*fz;
        float c10 = v100*(1.0f-fz) + v101*fz;
        float c11 = v110*(1.0f-fz) + v111*fz;
        float a0 = c00*(1.0f-fy) + c01*fy;
        float a1 = c10*(1.0f-fy) + c11*fy;
        float Ival = a0*(1.0f-fx) + a1*fx;
        IV[e] = Ival;
        sI[ty][4+dp+e] = Ival;
        sJ[ty][4+dp+e] = Y4[e];
        GX[e] = (1.0f-fy)*((v100-v000)*(1.0f-fz) + (v101-v001)*fz)
              +        fy*((v110-v010)*(1.0f-fz) + (v111-v011)*fz);
        GY[e] = (1.0f-fx)*((v010-v000)*(1.0f-fz) + (v011-v001)*fz)
              +        fx*((v110-v100)*(1.0f-fz) + (v111-v101)*fz);
        GZ[e] = (1.0f-fx)*((v001-v000)*(1.0f-fy) + (v011-v010)*fy)
              +        fx*((v101-v100)*(1.0f-fy) + (v111-v110)*fy);
    }
    st4nt(g_I + idx,          float4{IV[0],IV[1],IV[2],IV[3]});
    st4nt(g_G + idx,          float4{GX[0],GX[1],GX[2],GX[3]});
    st4nt(g_G + NPTS + idx,   float4{GY[0],GY[1],GY[2],GY[3]});
    st4nt(g_G + 2*NPTS + idx, float4{GZ[0],GZ[1],GZ[2],GZ[3]});

    if (tx == 0) {
#pragma unroll
        for (int j = 0; j < 4; j++) { sI[ty][j] = 0.f; sJ[ty][j] = 0.f; }
    }
    if (tx == 39) {
#pragma unroll
        for (int j = 164; j < 168; j++) { sI[ty][j] = 0.f; sJ[ty][j] = 0.f; }
    }
    __syncthreads();

    float tI[12], tJ[12];
    { float4 a = ld4(&sI[ty][dp]);   UNPK(a, (&tI[0])); }
    { float4 a = ld4(&sI[ty][dp+4]); UNPK(a, (&tI[4])); }
    { float4 a = ld4(&sI[ty][dp+8]); UNPK(a, (&tI[8])); }
    { float4 a = ld4(&sJ[ty][dp]);   UNPK(a, (&tJ[0])); }
    { float4 a = ld4(&sJ[ty][dp+4]); UNPK(a, (&tJ[4])); }
    { float4 a = ld4(&sJ[ty][dp+8]); UNPK(a, (&tJ[8])); }

    float s1a[4], s2a[4], s3a[4];
#pragma unroll
    for (int e = 0; e < 4; e++) {
        float s1 = 0.f, s2 = 0.f, s3 = 0.f;
#pragma unroll
        for (int j = 0; j < 9; j++) {
            float a = tI[e+j], b = tJ[e+j];
            s1 += a; s2 += a*a; s3 += a*b;
        }
        s1a[e] = s1; s2a[e] = s2; s3a[e] = s3;
    }
    st4nt(g_X + idx,          float4{s1a[0],s1a[1],s1a[2],s1a[3]});
    st4nt(g_X + NPTS + idx,   float4{s2a[0],s2a[1],s2a[2],s2a[3]});
    st4nt(g_X + 2*NPTS + idx, float4{s3a[0],s3a[1],s3a[2],s3a[3]});
}

// ========== k2/k4: W-axis box, one field per block (blockIdx.z) (g_X -> g_Y) ==========
__global__ void __launch_bounds__(256) boxW1_k()
{
    __shared__ __align__(16) float s[WW][32];
    int h  = blockIdx.x;
    int d0 = blockIdx.y*32;
    int f  = blockIdx.z;
    int t  = threadIdx.x;
    const float* base = g_X + f*NPTS + h*WD + d0;
    for (int q = t; q < WW*8; q += 256) {
        int wq = q >> 3, dq = (q & 7)*4;
        st4(&s[wq][dq], ld4nt(base + wq*DD + dq));
    }
    __syncthreads();
    float* ob = g_Y + f*NPTS + h*WD + d0;
    for (int q = t; q < WW*8; q += 256) {
        int wq = q >> 3, dq = (q & 7)*4;
        int lo = (wq < 4) ? -wq : -4;
        int hi = (wq > WW-5) ? (WW-1-wq) : 4;
        float4 acc = float4{0,0,0,0};
        for (int k = lo; k <= hi; k++) {
            float4 v = ld4(&s[wq+k][dq]);
            acc.x += v.x; acc.y += v.y; acc.z += v.z; acc.w += v.w;
        }
        st4nt(ob + wq*DD + dq, acc);
    }
}

// ======= k3: H-box(moments) + fields + H-box(fields) (g_Y -> g_X) =======
// d-chunk 16 (64 B sectors). LDS staging row sa (zero-halo) serves the 9 H-taps
// from LDS instead of L2. LDS 41.5 KB -> 3 blocks/CU.
__global__ void __launch_bounds__(256) boxH_fields_k()
{
    __shared__ __align__(16) float sa[(HH+8)*16];    // zero halo rows 0..3, HH+4..HH+7
    __shared__ __align__(16) float sf[3][HH*16];
    int w  = blockIdx.x;
    int d0 = blockIdx.y*16;
    int t  = threadIdx.x;

    // zero the 8 halo rows once (128 floats = 32 float4)
    if (t < 32) {
        int r = t >> 2, cq = (t & 3)*4;
        int row = (r < 4) ? r : (HH + r);
        st4(&sa[row*16 + cq], float4{0,0,0,0});
    }

    // Phase A: per field, stage column into sa then H-box (9 taps, zero-halo) -> sf
#pragma unroll
    for (int f = 0; f < 3; f++) {
        const float* base = g_Y + f*NPTS + w*DD + d0;
        __syncthreads();   // halo (first iter) / previous box reads done before restage
        for (int q = t; q < HH*4; q += 256) {
            int hh = q >> 2, dq = (q & 3)*4;
            st4(&sa[(hh+4)*16 + dq], ld4nt(base + hh*WD + dq));
        }
        __syncthreads();
        for (int q = t; q < HH*4; q += 256) {
            int hh = q >> 2, dq = (q & 3)*4;
            float4 acc = float4{0,0,0,0};
#pragma unroll
            for (int k = 0; k < 9; k++) {
                float4 v = ld4(&sa[(hh+k)*16 + dq]);
                acc.x += v.x; acc.y += v.y; acc.z += v.z; acc.w += v.w;
            }
            st4(&sf[f][hh*16 + dq], acc);
        }
    }
    __syncthreads();

    // Phase B: pointwise fields A,B,C — compute all, sync, then overwrite sf
    {
        float A_[3][4], B_[3][4], C_[3][4];   // q-loop has up to 3 iterations (640/256)
        int qi = 0;
        for (int q = t; q < HH*4; q += 256, qi++) {
            int hh = q >> 2, dq = (q & 3)*4;
            int idxg = hh*WD + w*DD + d0 + dq;
            float Is[4], I2s[4], IJs[4], UJ[4], JV[4];
            { float4 a = ld4(&sf[0][hh*16 + dq]); UNPK(a, Is); }
            { float4 a = ld4(&sf[1][hh*16 + dq]); UNPK(a, I2s); }
            { float4 a = ld4(&sf[2][hh*16 + dq]); UNPK(a, IJs); }
            { float4 a = ld4(g_uJ + idxg);        UNPK(a, UJ); }
            { float4 a = ld4(g_Jv + idxg);        UNPK(a, JV); }
#pragma unroll
            for (int e = 0; e < 4; e++) {
                float uI = Is[e] * INV_WSZ;
                float cross = IJs[e] - UJ[e]*Is[e];
                float Ivar  = I2s[e] - uI*Is[e];
                float den = Ivar*JV[e] + 1e-5f;
                float inv = 1.0f / den;
                float A = 2.0f*cross*inv;
                float B = -cross*cross*JV[e]*inv*inv;
                A_[qi][e] = A; B_[qi][e] = B; C_[qi][e] = A*UJ[e] + 2.0f*B*uI;
            }
        }
        __syncthreads();
        qi = 0;
        for (int q = t; q < HH*4; q += 256, qi++) {
            int hh = q >> 2, dq = (q & 3)*4;
            st4(&sf[0][hh*16 + dq], float4{A_[qi][0],A_[qi][1],A_[qi][2],A_[qi][3]});
            st4(&sf[1][hh*16 + dq], float4{B_[qi][0],B_[qi][1],B_[qi][2],B_[qi][3]});
            st4(&sf[2][hh*16 + dq], float4{C_[qi][0],C_[qi][1],C_[qi][2],C_[qi][3]});
        }
    }
    __syncthreads();

    // Phase C: H-box the fields (clipped window, same order as before) -> g_X
#pragma unroll
    for (int f = 0; f < 3; f++) {
        float* ob = g_X + f*NPTS + w*DD + d0;
        for (int q = t; q < HH*4; q += 256) {
            int hh = q >> 2, dq = (q & 3)*4;
            int lo = (hh < 4) ? -hh : -4;
            int hi = (hh > HH-5) ? (HH-1-hh) : 4;
            float4 acc = float4{0,0,0,0};
            for (int k = lo; k <= hi; k++) {
                float4 v = ld4(&sf[f][(hh+k)*16 + dq]);
                acc.x += v.x; acc.y += v.y; acc.z += v.z; acc.w += v.w;
            }
            st4nt(ob + hh*WD + dq, acc);
        }
    }
}

// ===== k5: LDS-staged D-box + (precomputed I, gx,gy,gz) + reg + Adam =====
// Block (40,8): 8 lines; g_Y field-lines staged in LDS with zero halo so the
// 9-tap D-box costs 3 NT global loads + LDS reads (was 9 global loads).
// FINAL=true (t=5): m/v/vh/fout stores dead; fuse MSE((flow-finit)^2) partials.
template<bool FINAL>
__global__ void __launch_bounds__(320) grad_adam_k(
        const float* __restrict__ y,
        const float* __restrict__ finit,
        int fin_code, int fout_code,
        float inv_bc1, float inv_sqrt_bc2, int is_first)
{
    __shared__ __align__(16) float sY[3][8][168];
    __shared__ double sd[FINAL ? 320 : 1];
    int tx = threadIdx.x;                 // 0..39
    int ty = threadIdx.y;                 // 0..7
    int line = blockIdx.x*8 + ty;
    int h = line / WW, w = line % WW;
    int dp = tx*4;
    int idx = line*DD + dp;
    const float* fin = (fin_code == 0) ? finit : ((fin_code == 1) ? g_flowA : g_flowB);
    float* fout = (fout_code == 1) ? g_flowA : g_flowB;

    // stage the 3 H,W-boxed field lines (zero halo = conv zero-padding semantics)
#pragma unroll
    for (int f = 0; f < 3; f++)
        st4(&sY[f][ty][4+dp], ld4nt(g_Y + f*NPTS + idx));
    if (tx == 0) {
#pragma unroll
        for (int f = 0; f < 3; f++) st4(&sY[f][ty][0], float4{0,0,0,0});
    }
    if (tx == 39) {
#pragma unroll
        for (int f = 0; f < 3; f++) st4(&sY[f][ty][164], float4{0,0,0,0});
    }
    __syncthreads();

    float SA[4], SB[4], SC[4];
    {
        float tW[12];
        { float4 a = ld4(&sY[0][ty][dp]);   UNPK(a, (&tW[0])); }
        { float4 a = ld4(&sY[0][ty][dp+4]); UNPK(a, (&tW[4])); }
        { float4 a = ld4(&sY[0][ty][dp+8]); UNPK(a, (&tW[8])); }
#pragma unroll
        for (int e = 0; e < 4; e++) { float s=0.f;
#pragma unroll
            for (int j = 0; j < 9; j++) s += tW[e+j]; SA[e]=s; }
        { float4 a = ld4(&sY[1][ty][dp]);   UNPK(a, (&tW[0])); }
        { float4 a = ld4(&sY[1][ty][dp+4]); UNPK(a, (&tW[4])); }
        { float4 a = ld4(&sY[1][ty][dp+8]); UNPK(a, (&tW[8])); }
#pragma unroll
        for (int e = 0; e < 4; e++) { float s=0.f;
#pragma unroll
            for (int j = 0; j < 9; j++) s += tW[e+j]; SB[e]=s; }
        { float4 a = ld4(&sY[2][ty][dp]);   UNPK(a, (&tW[0])); }
        { float4 a = ld4(&sY[2][ty][dp+4]); UNPK(a, (&tW[4])); }
        { float4 a = ld4(&sY[2][ty][dp+8]); UNPK(a, (&tW[8])); }
#pragma unroll
        for (int e = 0; e < 4; e++) { float s=0.f;
#pragma unroll
            for (int j = 0; j < 9; j++) s += tW[e+j]; SC[e]=s; }
    }

    float F[3][4];
    { float4 a = ld4(fin + idx);          UNPK(a, F[0]); }
    { float4 a = ld4(fin + NPTS + idx);   UNPK(a, F[1]); }
    { float4 a = ld4(fin + 2*NPTS + idx); UNPK(a, F[2]); }
    float Y4[4], I4[4], GX[4], GY[4], GZ[4];
    { float4 a = ld4(y + idx);              UNPK(a, Y4); }
    { float4 a = ld4nt(g_I + idx);          UNPK(a, I4); }
    { float4 a = ld4nt(g_G + idx);          UNPK(a, GX); }
    { float4 a = ld4nt(g_G + NPTS + idx);   UNPK(a, GY); }
    { float4 a = ld4nt(g_G + 2*NPTS + idx); UNPK(a, GZ); }

    float GS[3][4];
#pragma unroll
    for (int e = 0; e < 4; e++) {
        float gI = -(1.0f/(float)NPTS) * (Y4[e]*SA[e] + 2.0f*I4[e]*SB[e] - SC[e]);
        GS[0][e] = gI*GX[e]; GS[1][e] = gI*GY[e]; GS[2][e] = gI*GZ[e];
    }

    const float coefH = 2.0f / (3.0f * (float)(3*(HH-1)*WW*DD));
    const float coefW = 2.0f / (3.0f * (float)(3*HH*(WW-1)*DD));
    const float coefD = 2.0f / (3.0f * (float)(3*HH*WW*(DD-1)));

    double msea = 0.0;

#pragma unroll
    for (int c = 0; c < 3; c++) {
        const float* fc = fin + c*NPTS;
        int o = c*NPTS + idx;
        float FU[4], FD[4], FL[4], FR[4];
        { float4 a = (h > 0)    ? ld4(fc + idx - WD) : float4{0,0,0,0}; UNPK(a, FU); }
        { float4 a = (h < HH-1) ? ld4(fc + idx + WD) : float4{0,0,0,0}; UNPK(a, FD); }
        { float4 a = (w > 0)    ? ld4(fc + idx - DD) : float4{0,0,0,0}; UNPK(a, FL); }
        { float4 a = (w < WW-1) ? ld4(fc + idx + DD) : float4{0,0,0,0}; UNPK(a, FR); }
        float dl = (dp > 0)     ? fc[idx - 1] : 0.f;
        float dr = (dp < DD-4)  ? fc[idx + 4] : 0.f;

        float M[4], V[4], VH[4];
        if (is_first) {
#pragma unroll
            for (int e = 0; e < 4; e++) { M[e]=0.f; V[e]=0.f; VH[e]=0.f; }
        } else {
            { float4 a = ld4nt(g_m  + o); UNPK(a, M); }
            { float4 a = ld4nt(g_v  + o); UNPK(a, V); }
            { float4 a = ld4nt(g_vh + o); UNPK(a, VH); }
        }

        float FI[4];
        if (FINAL) { float4 a = ld4(finit + o); UNPK(a, FI); }

        float O[4];
#pragma unroll
        for (int e = 0; e < 4; e++) {
            int d = dp + e;
            float f0 = F[c][e];
            float r = 0.0f;
            if (h > 0)     r += coefH*(f0 - FU[e]);
            if (h < HH-1)  r -= coefH*(FD[e] - f0);
            if (w > 0)     r += coefW*(f0 - FL[e]);
            if (w < WW-1)  r -= coefW*(FR[e] - f0);
            float left  = (e == 0) ? dl : F[c][e-1];
            float right = (e == 3) ? dr : F[c][e+1];
            if (d > 0)     r += coefD*(f0 - left);
            if (d < DD-1)  r -= coefD*(right - f0);
            float g = GS[c][e] + r;

            float mm  = ADAM_B1*M[e]  + (1.0f - ADAM_B1)*g;
            float vv  = ADAM_B2*V[e]  + (1.0f - ADAM_B2)*g*g;
            float vhh = fmaxf(VH[e], vv);
            M[e] = mm; V[e] = vv; VH[e] = vhh;
            float den = sqrtf(vhh)*inv_sqrt_bc2 + ADAM_EPS;
            O[e] = f0 - ADAM_LR*(mm*inv_bc1)/den;
            if (FINAL) {
                float df = O[e] - FI[e];
                msea += (double)df * (double)df;
            }
        }
        if (!FINAL) {
            st4nt(g_m  + o, float4{M[0],M[1],M[2],M[3]});
            st4nt(g_v  + o, float4{V[0],V[1],V[2],V[3]});
            st4nt(g_vh + o, float4{VH[0],VH[1],VH[2],VH[3]});
            st4(fout + o, float4{O[0],O[1],O[2],O[3]});
        }
    }

    if (FINAL) {
        int tid = ty*40 + tx;
        sd[tid] = msea; __syncthreads();
        if (tid < 160) sd[tid] += sd[tid + 160]; __syncthreads();
        if (tid < 80)  sd[tid] += sd[tid + 80];  __syncthreads();
        if (tid < 40)  sd[tid] += sd[tid + 40];  __syncthreads();
        if (tid < 20)  sd[tid] += sd[tid + 20];  __syncthreads();
        if (tid < 10)  sd[tid] += sd[tid + 10];  __syncthreads();
        if (tid < 5)   sd[tid] += sd[tid + 5];   __syncthreads();
        if (tid == 0) g_part[blockIdx.x] = sd[0] + sd[1] + sd[2] + sd[3] + sd[4];
    }
}

// ================= pre-loop J stats =================

__global__ void jmomD_k(const float* __restrict__ J)
{
    __shared__ float sJ[2][DD];
    int tx = threadIdx.x, ty = threadIdx.y;
    int line = blockIdx.x*2 + ty;
    int idx = line*DD + tx;
    sJ[ty][tx] = J[idx];
    __syncthreads();
    int lo = (tx < 4) ? -tx : -4;
    int hi = (tx > DD-5) ? (DD-1-tx) : 4;
    float s1 = 0.f, s2 = 0.f;
    for (int k = lo; k <= hi; k++) {
        float b = sJ[ty][tx+k];
        s1 += b; s2 += b*b;
    }
    g_X[idx] = s1; g_X[NPTS + idx] = s2;
}

__global__ void __launch_bounds__(256) boxH2_jstats_k()
{
    int p = blockIdx.x*blockDim.x + threadIdx.x;
    if (p >= NP4) return;
    int idx = p*4;
    int h = idx / WD;
    int lo = (h < 4) ? -h : -4;
    int hi = (h > HH-5) ? (HH-1-h) : 4;
    float4 s1 = float4{0,0,0,0}, s2 = float4{0,0,0,0};
    for (int k = lo; k <= hi; k++) {
        float4 a = ld4(g_Y + idx + k*WD);
        float4 b = ld4(g_Y + NPTS + idx + k*WD);
        s1.x += a.x; s1.y += a.y; s1.z += a.z; s1.w += a.w;
        s2.x += b.x; s2.y += b.y; s2.z += b.z; s2.w += b.w;
    }
    float4 u  = float4{s1.x*INV_WSZ, s1.y*INV_WSZ, s1.z*INV_WSZ, s1.w*INV_WSZ};
    float4 jv = float4{s2.x - u.x*s1.x, s2.y - u.y*s1.y, s2.z - u.z*s1.z, s2.w - u.w*s1.w};
    st4(g_uJ + idx, u);
    st4(g_Jv + idx, jv);
}

// ================= final MSE fold =================

__global__ void mse_final_k(int nblk, float* __restrict__ out)
{
    __shared__ double sd[256];
    int tid = threadIdx.x;
    double s = 0.0;
    for (int i = tid; i < nblk; i += 256) s += g_part[i];
    sd[tid] = s; __syncthreads();
    for (int o = 128; o > 0; o >>= 1) {
        if (tid < o) sd[tid] += sd[tid + o];
        __syncthreads();
    }
    if (tid == 0) out[0] = (float)(sd[0] / (3.0*(double)NPTS));
}

// ================= launch =================

extern "C" void kernel_launch(void* const* d_in, const int* in_sizes, int n_in,
                              void* d_out, int out_size, void* d_ws, size_t ws_size,
                              hipStream_t stream)
{
    const float* x    = (const float*)d_in[0];
    const float* y    = (const float*)d_in[1];
    const float* finit= (const float*)d_in[2];
    (void)d_ws; (void)ws_size;

    dim3 blk(256);
    dim3 grd4((NP4 + 255)/256);
    dim3 lineBlk(DD, 2);
    dim3 lineGrd(HH*WW/2);
    dim3 wGrd2(HH, DD/32, 2);
    dim3 wGrd3(HH, DD/32, 3);
    dim3 hGrd(WW, DD/16);
    dim3 wmBlk(40, 8);
    dim3 wmGrd(HH*WW/8);

    // J-side stats (flow-independent)
    jmomD_k<<<lineGrd, lineBlk, 0, stream>>>(y);
    boxW1_k<<<wGrd2, blk, 0, stream>>>();              // X -> Y (W), 2 fields
    boxH2_jstats_k<<<grd4, blk, 0, stream>>>();        // Y -> uJ, Jv (H inline)

    // fin/fout codes: 0 = finit, 1 = g_flowA, 2 = g_flowB
    int fin_code = 0, fout_code = 1;
    for (int t = 1; t <= 5; t++) {
        warp_momD_k<<<wmGrd, wmBlk, 0, stream>>>(x, y, finit, fin_code); // -> X, g_I, g_G
        boxW1_k<<<wGrd3, blk, 0, stream>>>();                            // X -> Y (W)
        boxH_fields_k<<<hGrd, blk, 0, stream>>>();                       // Y -> X (H, fields, H)
        boxW1_k<<<wGrd3, blk, 0, stream>>>();                            // X -> Y (W)
        double bc1 = 1.0 - pow(0.9, (double)t);
        double bc2 = 1.0 - pow(0.999, (double)t);
        if (t < 5) {
            grad_adam_k<false><<<wmGrd, wmBlk, 0, stream>>>(y, finit, fin_code, fout_code,
                                                            (float)(1.0/bc1), (float)(1.0/sqrt(bc2)),
                                                            (t == 1) ? 1 : 0);
        } else {
            grad_adam_k<true><<<wmGrd, wmBlk, 0, stream>>>(y, finit, fin_code, fout_code,
                                                           (float)(1.0/bc1), (float)(1.0/sqrt(bc2)), 0);
        }
        fin_code = fout_code;
        fout_code = (fout_code == 1) ? 2 : 1;
    }

    mse_final_k<<<1, blk, 0, stream>>>(NBLK_FINAL, (float*)d_out);
}

// Round 10
// 1815.481 us; speedup vs baseline: 1.1500x; 1.1500x over previous
//
#include <hip/hip_runtime.h>
#include <cmath>

// Problem geometry (fixed by setup_inputs)
#define HH 160
#define WW 192
#define DD 160
#define WD (WW*DD)          // 30720
#define NPTS (HH*WW*DD)     // 4,915,200
#define NP4  (NPTS/4)
#define INV_WSZ (1.0f/729.0f)
#define ADAM_B1 0.9f
#define ADAM_B2 0.999f
#define ADAM_LR 0.1f
#define ADAM_EPS 1e-8f
#define NBLK_FINAL 4800     // NP4/256 exactly

// ---------------- persistent device-global scratch (~460 MB) ----------------
__device__ __align__(16) float g_flowA[3*NPTS];
__device__ __align__(16) float g_flowB[3*NPTS];
__device__ __align__(16) float g_m   [3*NPTS];
__device__ __align__(16) float g_v   [3*NPTS];
__device__ __align__(16) float g_vh  [3*NPTS];
__device__ __align__(16) float g_X   [3*NPTS];
__device__ __align__(16) float g_Y   [3*NPTS];
__device__ __align__(16) float g_I   [NPTS];     // trilinear value at fin
__device__ __align__(16) float g_G   [3*NPTS];   // trilinear coord-gradients at fin
__device__ __align__(16) float g_uJ  [NPTS];
__device__ __align__(16) float g_Jv  [NPTS];
__device__ double g_part[8192];

// ---------------- helpers ----------------

typedef float nat4 __attribute__((ext_vector_type(4)));  // native clang vector for NT builtins

__device__ __forceinline__ float4 ld4(const float* p) { return *reinterpret_cast<const float4*>(p); }
__device__ __forceinline__ void  st4(float* p, float4 v) { *reinterpret_cast<float4*>(p) = v; }
__device__ __forceinline__ float4 ld4nt(const float* p) {
    nat4 t = __builtin_nontemporal_load(reinterpret_cast<const nat4*>(p));
    return float4{t.x, t.y, t.z, t.w};
}
__device__ __forceinline__ void st4nt(float* p, float4 v) {
    nat4 t = {v.x, v.y, v.z, v.w};
    __builtin_nontemporal_store(t, reinterpret_cast<nat4*>(p));
}
#define UNPK(V,A) { A[0]=(V).x; A[1]=(V).y; A[2]=(V).z; A[3]=(V).w; }

__device__ __forceinline__ float fetchx(const float* __restrict__ x, int i, int j, int k) {
    if ((unsigned)i >= (unsigned)HH || (unsigned)j >= (unsigned)WW || (unsigned)k >= (unsigned)DD)
        return 0.0f;
    return x[(i*WW + j)*DD + k];
}

// 12-float window [idx-4, idx+8) with zero-padding at line edges (fp-exact clip).
__device__ __forceinline__ void load12(const float* base, int idx, int dp, float* t) {
    float4 a = (dp == 0)    ? float4{0,0,0,0} : ld4(base + idx - 4);
    float4 b = ld4(base + idx);
    float4 c = (dp == DD-4) ? float4{0,0,0,0} : ld4(base + idx + 4);
    t[0]=a.x; t[1]=a.y; t[2]=a.z; t[3]=a.w;
    t[4]=b.x; t[5]=b.y; t[6]=b.z; t[7]=b.w;
    t[8]=c.x; t[9]=c.y; t[10]=c.z; t[11]=c.w;
}

// ====== k1: fused warp + trilinear gradients + D-axis box of (I, I^2, I*J) ======
__global__ void __launch_bounds__(320) warp_momD_k(
        const float* __restrict__ x, const float* __restrict__ y,
        const float* __restrict__ finit, int fin_code)
{
    __shared__ __align__(16) float sI[8][168];   // 4 zero-pad front/back
    __shared__ __align__(16) float sJ[8][168];
    int tx = threadIdx.x;                 // 0..39
    int ty = threadIdx.y;                 // 0..7
    int line = blockIdx.x*8 + ty;         // h*WW + w
    int h = line / WW, w = line % WW;
    int dp = tx*4;
    int idx = line*DD + dp;
    const float* fin = (fin_code == 0) ? finit : ((fin_code == 1) ? g_flowA : g_flowB);

    float F0[4], F1[4], F2[4], Y4[4];
    { float4 a = ld4(fin + idx);          UNPK(a, F0); }
    { float4 a = ld4(fin + NPTS + idx);   UNPK(a, F1); }
    { float4 a = ld4(fin + 2*NPTS + idx); UNPK(a, F2); }
    { float4 a = ld4(y + idx);            UNPK(a, Y4); }

    float GX[4], GY[4], GZ[4], IV[4];
#pragma unroll
    for (int e = 0; e < 4; e++) {
        float c0 = (float)h + F0[e];
        float c1 = (float)w + F1[e];
        float c2 = (float)(dp + e) + F2[e];
        float fl0 = floorf(c0), fl1 = floorf(c1), fl2 = floorf(c2);
        int i0 = (int)fl0, j0 = (int)fl1, k0 = (int)fl2;
        float fx = c0 - fl0, fy = c1 - fl1, fz = c2 - fl2;
        float v000 = fetchx(x, i0,   j0,   k0  ), v001 = fetchx(x, i0,   j0,   k0+1);
        float v010 = fetchx(x, i0,   j0+1, k0  ), v011 = fetchx(x, i0,   j0+1, k0+1);
        float v100 = fetchx(x, i0+1, j0,   k0  ), v101 = fetchx(x, i0+1, j0,   k0+1);
        float v110 = fetchx(x, i0+1, j0+1, k0  ), v111 = fetchx(x, i0+1, j0+1, k0+1);
        float c00 = v000*(1.0f-fz) + v001*fz;
        float c01 = v010*(1.0f-fz) + v011*fz;
        float c10 = v100*(1.0f-fz) + v101*fz;
        float c11 = v110*(1.0f-fz) + v111*fz;
        float a0 = c00*(1.0f-fy) + c01*fy;
        float a1 = c10*(1.0f-fy) + c11*fy;
        float Ival = a0*(1.0f-fx) + a1*fx;
        IV[e] = Ival;
        sI[ty][4+dp+e] = Ival;
        sJ[ty][4+dp+e] = Y4[e];
        GX[e] = (1.0f-fy)*((v100-v000)*(1.0f-fz) + (v101-v001)*fz)
              +        fy*((v110-v010)*(1.0f-fz) + (v111-v011)*fz);
        GY[e] = (1.0f-fx)*((v010-v000)*(1.0f-fz) + (v011-v001)*fz)
              +        fx*((v110-v100)*(1.0f-fz) + (v111-v101)*fz);
        GZ[e] = (1.0f-fx)*((v001-v000)*(1.0f-fy) + (v011-v010)*fy)
              +        fx*((v101-v100)*(1.0f-fy) + (v111-v110)*fy);
    }
    st4nt(g_I + idx,          float4{IV[0],IV[1],IV[2],IV[3]});
    st4nt(g_G + idx,          float4{GX[0],GX[1],GX[2],GX[3]});
    st4nt(g_G + NPTS + idx,   float4{GY[0],GY[1],GY[2],GY[3]});
    st4nt(g_G + 2*NPTS + idx, float4{GZ[0],GZ[1],GZ[2],GZ[3]});

    if (tx == 0) {
#pragma unroll
        for (int j = 0; j < 4; j++) { sI[ty][j] = 0.f; sJ[ty][j] = 0.f; }
    }
    if (tx == 39) {
#pragma unroll
        for (int j = 164; j < 168; j++) { sI[ty][j] = 0.f; sJ[ty][j] = 0.f; }
    }
    __syncthreads();

    float tI[12], tJ[12];
    { float4 a = ld4(&sI[ty][dp]);   UNPK(a, (&tI[0])); }
    { float4 a = ld4(&sI[ty][dp+4]); UNPK(a, (&tI[4])); }
    { float4 a = ld4(&sI[ty][dp+8]); UNPK(a, (&tI[8])); }
    { float4 a = ld4(&sJ[ty][dp]);   UNPK(a, (&tJ[0])); }
    { float4 a = ld4(&sJ[ty][dp+4]); UNPK(a, (&tJ[4])); }
    { float4 a = ld4(&sJ[ty][dp+8]); UNPK(a, (&tJ[8])); }

    float s1a[4], s2a[4], s3a[4];
#pragma unroll
    for (int e = 0; e < 4; e++) {
        float s1 = 0.f, s2 = 0.f, s3 = 0.f;
#pragma unroll
        for (int j = 0; j < 9; j++) {
            float a = tI[e+j], b = tJ[e+j];
            s1 += a; s2 += a*a; s3 += a*b;
        }
        s1a[e] = s1; s2a[e] = s2; s3a[e] = s3;
    }
    st4nt(g_X + idx,          float4{s1a[0],s1a[1],s1a[2],s1a[3]});
    st4nt(g_X + NPTS + idx,   float4{s2a[0],s2a[1],s2a[2],s2a[3]});
    st4nt(g_X + 2*NPTS + idx, float4{s3a[0],s3a[1],s3a[2],s3a[3]});
}

// ================= k2/k4: W-axis box via LDS plane tile (g_X -> g_Y) =================
template<int NF>
__global__ void __launch_bounds__(256) boxW_k()
{
    __shared__ __align__(16) float s[WW][32];
    int h  = blockIdx.x;
    int d0 = blockIdx.y*32;
    int t  = threadIdx.x;
#pragma unroll
    for (int f = 0; f < NF; f++) {
        const float* base = g_X + f*NPTS + h*WD + d0;
        for (int q = t; q < WW*8; q += 256) {
            int wq = q >> 3, dq = (q & 7)*4;
            st4(&s[wq][dq], ld4nt(base + wq*DD + dq));
        }
        __syncthreads();
        float* ob = g_Y + f*NPTS + h*WD + d0;
        for (int q = t; q < WW*8; q += 256) {
            int wq = q >> 3, dq = (q & 7)*4;
            int lo = (wq < 4) ? -wq : -4;
            int hi = (wq > WW-5) ? (WW-1-wq) : 4;
            float4 acc = float4{0,0,0,0};
            for (int k = lo; k <= hi; k++) {
                float4 v = ld4(&s[wq+k][dq]);
                acc.x += v.x; acc.y += v.y; acc.z += v.z; acc.w += v.w;
            }
            st4nt(ob + wq*DD + dq, acc);
        }
        __syncthreads();
    }
}

// ======= k3: H-box(moments) + fields + H-box(fields) (g_Y -> g_X) =======
// d-chunk 16 (64 B per H-line: full sector use). No staging buffer — the 9
// H-taps read global directly; per-field column (10 KB) is L1-resident.
// LDS 30.7 KB -> 5 blocks/CU.
__global__ void __launch_bounds__(256) boxH_fields_k()
{
    __shared__ __align__(16) float sf[3][HH][16];
    int w  = blockIdx.x;
    int d0 = blockIdx.y*16;
    int t  = threadIdx.x;

    // Phase A: H-box each moment field straight from global (L1 reuse on taps)
#pragma unroll
    for (int f = 0; f < 3; f++) {
        const float* base = g_Y + f*NPTS + w*DD + d0;
        for (int q = t; q < HH*4; q += 256) {
            int hh = q >> 2, dq = (q & 3)*4;
            int lo = (hh < 4) ? -hh : -4;
            int hi = (hh > HH-5) ? (HH-1-hh) : 4;
            float4 acc = float4{0,0,0,0};
            for (int k = lo; k <= hi; k++) {
                float4 v = ld4(base + (hh+k)*WD + dq);
                acc.x += v.x; acc.y += v.y; acc.z += v.z; acc.w += v.w;
            }
            st4(&sf[f][hh][dq], acc);
        }
    }
    __syncthreads();

    // Phase B: pointwise fields A,B,C — compute all, sync, then overwrite.
    // q-loop runs up to 3 iterations (HH*4=640 / 256) -> arrays sized [3][4].
    {
        float A_[3][4], B_[3][4], C_[3][4];
        int qi = 0;
        for (int q = t; q < HH*4; q += 256, qi++) {
            int hh = q >> 2, dq = (q & 3)*4;
            int idxg = hh*WD + w*DD + d0 + dq;
            float Is[4], I2s[4], IJs[4], UJ[4], JV[4];
            { float4 a = ld4(&sf[0][hh][dq]); UNPK(a, Is); }
            { float4 a = ld4(&sf[1][hh][dq]); UNPK(a, I2s); }
            { float4 a = ld4(&sf[2][hh][dq]); UNPK(a, IJs); }
            { float4 a = ld4(g_uJ + idxg);    UNPK(a, UJ); }
            { float4 a = ld4(g_Jv + idxg);    UNPK(a, JV); }
#pragma unroll
            for (int e = 0; e < 4; e++) {
                float uI = Is[e] * INV_WSZ;
                float cross = IJs[e] - UJ[e]*Is[e];
                float Ivar  = I2s[e] - uI*Is[e];
                float den = Ivar*JV[e] + 1e-5f;
                float inv = 1.0f / den;
                float A = 2.0f*cross*inv;
                float B = -cross*cross*JV[e]*inv*inv;
                A_[qi][e] = A; B_[qi][e] = B; C_[qi][e] = A*UJ[e] + 2.0f*B*uI;
            }
        }
        __syncthreads();
        qi = 0;
        for (int q = t; q < HH*4; q += 256, qi++) {
            int hh = q >> 2, dq = (q & 3)*4;
            st4(&sf[0][hh][dq], float4{A_[qi][0],A_[qi][1],A_[qi][2],A_[qi][3]});
            st4(&sf[1][hh][dq], float4{B_[qi][0],B_[qi][1],B_[qi][2],B_[qi][3]});
            st4(&sf[2][hh][dq], float4{C_[qi][0],C_[qi][1],C_[qi][2],C_[qi][3]});
        }
    }
    __syncthreads();

    // Phase C: H-box the fields -> g_X
#pragma unroll
    for (int f = 0; f < 3; f++) {
        float* ob = g_X + f*NPTS + w*DD + d0;
        for (int q = t; q < HH*4; q += 256) {
            int hh = q >> 2, dq = (q & 3)*4;
            int lo = (hh < 4) ? -hh : -4;
            int hi = (hh > HH-5) ? (HH-1-hh) : 4;
            float4 acc = float4{0,0,0,0};
            for (int k = lo; k <= hi; k++) {
                float4 v = ld4(&sf[f][hh+k][dq]);
                acc.x += v.x; acc.y += v.y; acc.z += v.z; acc.w += v.w;
            }
            st4nt(ob + hh*WD + dq, acc);
        }
    }
}

// ===== k5: inline D-box + (precomputed I, gx,gy,gz) + reg + Adam =====
// FINAL=true (t=5): m/v/vh/fout stores are dead; fuse MSE((flow_new - finit)^2)
// as per-block double partials instead.
template<bool FINAL>
__global__ void __launch_bounds__(256) grad_adam_k(
        const float* __restrict__ y,
        const float* __restrict__ finit,
        int fin_code, int fout_code,
        float inv_bc1, float inv_sqrt_bc2, int is_first)
{
    __shared__ double sd[256];
    int p = blockIdx.x*blockDim.x + threadIdx.x;   // pack of 4 voxels along d
    if (p >= NP4) return;
    int line = p / (DD/4);
    int dp   = (p % (DD/4))*4;
    int idx  = line*DD + dp;
    int w = line % WW;
    int h = line / WW;
    const float* fin = (fin_code == 0) ? finit : ((fin_code == 1) ? g_flowA : g_flowB);
    float* fout = (fout_code == 1) ? g_flowA : g_flowB;

    // ---- D-box of the H,W-boxed fields (12-float window, zero-padded) ----
    float SA[4], SB[4], SC[4];
    {
        float t[12];
        load12(g_Y,          idx, dp, t);
#pragma unroll
        for (int e = 0; e < 4; e++) { float s=0.f;
#pragma unroll
            for (int j = 0; j < 9; j++) s += t[e+j]; SA[e]=s; }
        load12(g_Y + NPTS,   idx, dp, t);
#pragma unroll
        for (int e = 0; e < 4; e++) { float s=0.f;
#pragma unroll
            for (int j = 0; j < 9; j++) s += t[e+j]; SB[e]=s; }
        load12(g_Y + 2*NPTS, idx, dp, t);
#pragma unroll
        for (int e = 0; e < 4; e++) { float s=0.f;
#pragma unroll
            for (int j = 0; j < 9; j++) s += t[e+j]; SC[e]=s; }
    }

    float F[3][4];
    { float4 a = ld4(fin + idx);          UNPK(a, F[0]); }
    { float4 a = ld4(fin + NPTS + idx);   UNPK(a, F[1]); }
    { float4 a = ld4(fin + 2*NPTS + idx); UNPK(a, F[2]); }
    float Y4[4], I4[4], GX[4], GY[4], GZ[4];
    { float4 a = ld4(y + idx);              UNPK(a, Y4); }
    { float4 a = ld4nt(g_I + idx);          UNPK(a, I4); }
    { float4 a = ld4nt(g_G + idx);          UNPK(a, GX); }
    { float4 a = ld4nt(g_G + NPTS + idx);   UNPK(a, GY); }
    { float4 a = ld4nt(g_G + 2*NPTS + idx); UNPK(a, GZ); }

    float GS[3][4];
#pragma unroll
    for (int e = 0; e < 4; e++) {
        float gI = -(1.0f/(float)NPTS) * (Y4[e]*SA[e] + 2.0f*I4[e]*SB[e] - SC[e]);
        GS[0][e] = gI*GX[e]; GS[1][e] = gI*GY[e]; GS[2][e] = gI*GZ[e];
    }

    const float coefH = 2.0f / (3.0f * (float)(3*(HH-1)*WW*DD));
    const float coefW = 2.0f / (3.0f * (float)(3*HH*(WW-1)*DD));
    const float coefD = 2.0f / (3.0f * (float)(3*HH*WW*(DD-1)));

    double msea = 0.0;

#pragma unroll
    for (int c = 0; c < 3; c++) {
        const float* fc = fin + c*NPTS;
        int o = c*NPTS + idx;
        float FU[4], FD[4], FL[4], FR[4];
        { float4 a = (h > 0)    ? ld4(fc + idx - WD) : float4{0,0,0,0}; UNPK(a, FU); }
        { float4 a = (h < HH-1) ? ld4(fc + idx + WD) : float4{0,0,0,0}; UNPK(a, FD); }
        { float4 a = (w > 0)    ? ld4(fc + idx - DD) : float4{0,0,0,0}; UNPK(a, FL); }
        { float4 a = (w < WW-1) ? ld4(fc + idx + DD) : float4{0,0,0,0}; UNPK(a, FR); }
        float dl = (dp > 0)     ? fc[idx - 1] : 0.f;
        float dr = (dp < DD-4)  ? fc[idx + 4] : 0.f;

        float M[4], V[4], VH[4];
        if (is_first) {
#pragma unroll
            for (int e = 0; e < 4; e++) { M[e]=0.f; V[e]=0.f; VH[e]=0.f; }
        } else {
            { float4 a = ld4nt(g_m  + o); UNPK(a, M); }
            { float4 a = ld4nt(g_v  + o); UNPK(a, V); }
            { float4 a = ld4nt(g_vh + o); UNPK(a, VH); }
        }

        float FI[4];
        if (FINAL) { float4 a = ld4(finit + o); UNPK(a, FI); }

        float O[4];
#pragma unroll
        for (int e = 0; e < 4; e++) {
            int d = dp + e;
            float f0 = F[c][e];
            float r = 0.0f;
            if (h > 0)     r += coefH*(f0 - FU[e]);
            if (h < HH-1)  r -= coefH*(FD[e] - f0);
            if (w > 0)     r += coefW*(f0 - FL[e]);
            if (w < WW-1)  r -= coefW*(FR[e] - f0);
            float left  = (e == 0) ? dl : F[c][e-1];
            float right = (e == 3) ? dr : F[c][e+1];
            if (d > 0)     r += coefD*(f0 - left);
            if (d < DD-1)  r -= coefD*(right - f0);
            float g = GS[c][e] + r;

            float mm  = ADAM_B1*M[e]  + (1.0f - ADAM_B1)*g;
            float vv  = ADAM_B2*V[e]  + (1.0f - ADAM_B2)*g*g;
            float vhh = fmaxf(VH[e], vv);
            M[e] = mm; V[e] = vv; VH[e] = vhh;
            float den = sqrtf(vhh)*inv_sqrt_bc2 + ADAM_EPS;
            O[e] = f0 - ADAM_LR*(mm*inv_bc1)/den;
            if (FINAL) {
                float df = O[e] - FI[e];
                msea += (double)df * (double)df;
            }
        }
        if (!FINAL) {
            st4nt(g_m  + o, float4{M[0],M[1],M[2],M[3]});
            st4nt(g_v  + o, float4{V[0],V[1],V[2],V[3]});
            st4nt(g_vh + o, float4{VH[0],VH[1],VH[2],VH[3]});
            st4(fout + o, float4{O[0],O[1],O[2],O[3]});
        }
    }

    if (FINAL) {
        int tid = threadIdx.x;
        sd[tid] = msea; __syncthreads();
        for (int o2 = 128; o2 > 0; o2 >>= 1) {
            if (tid < o2) sd[tid] += sd[tid + o2];
            __syncthreads();
        }
        if (tid == 0) g_part[blockIdx.x] = sd[0];
    }
}

// ================= pre-loop J stats =================

__global__ void jmomD_k(const float* __restrict__ J)
{
    __shared__ float sJ[2][DD];
    int tx = threadIdx.x, ty = threadIdx.y;
    int line = blockIdx.x*2 + ty;
    int idx = line*DD + tx;
    sJ[ty][tx] = J[idx];
    __syncthreads();
    int lo = (tx < 4) ? -tx : -4;
    int hi = (tx > DD-5) ? (DD-1-tx) : 4;
    float s1 = 0.f, s2 = 0.f;
    for (int k = lo; k <= hi; k++) {
        float b = sJ[ty][tx+k];
        s1 += b; s2 += b*b;
    }
    g_X[idx] = s1; g_X[NPTS + idx] = s2;
}

__global__ void __launch_bounds__(256) boxH2_jstats_k()
{
    int p = blockIdx.x*blockDim.x + threadIdx.x;
    if (p >= NP4) return;
    int idx = p*4;
    int h = idx / WD;
    int lo = (h < 4) ? -h : -4;
    int hi = (h > HH-5) ? (HH-1-h) : 4;
    float4 s1 = float4{0,0,0,0}, s2 = float4{0,0,0,0};
    for (int k = lo; k <= hi; k++) {
        float4 a = ld4(g_Y + idx + k*WD);
        float4 b = ld4(g_Y + NPTS + idx + k*WD);
        s1.x += a.x; s1.y += a.y; s1.z += a.z; s1.w += a.w;
        s2.x += b.x; s2.y += b.y; s2.z += b.z; s2.w += b.w;
    }
    float4 u  = float4{s1.x*INV_WSZ, s1.y*INV_WSZ, s1.z*INV_WSZ, s1.w*INV_WSZ};
    float4 jv = float4{s2.x - u.x*s1.x, s2.y - u.y*s1.y, s2.z - u.z*s1.z, s2.w - u.w*s1.w};
    st4(g_uJ + idx, u);
    st4(g_Jv + idx, jv);
}

// ================= final MSE fold =================

__global__ void mse_final_k(int nblk, float* __restrict__ out)
{
    __shared__ double sd[256];
    int tid = threadIdx.x;
    double s = 0.0;
    for (int i = tid; i < nblk; i += 256) s += g_part[i];
    sd[tid] = s; __syncthreads();
    for (int o = 128; o > 0; o >>= 1) {
        if (tid < o) sd[tid] += sd[tid + o];
        __syncthreads();
    }
    if (tid == 0) out[0] = (float)(sd[0] / (3.0*(double)NPTS));
}

// ================= launch =================

extern "C" void kernel_launch(void* const* d_in, const int* in_sizes, int n_in,
                              void* d_out, int out_size, void* d_ws, size_t ws_size,
                              hipStream_t stream)
{
    const float* x    = (const float*)d_in[0];
    const float* y    = (const float*)d_in[1];
    const float* finit= (const float*)d_in[2];
    (void)d_ws; (void)ws_size;

    dim3 blk(256);
    dim3 grd4((NP4 + 255)/256);           // 4800 blocks exactly
    dim3 lineBlk(DD, 2);
    dim3 lineGrd(HH*WW/2);
    dim3 wBlk(256);
    dim3 wGrd(HH, DD/32);
    dim3 hGrd(WW, DD/16);
    dim3 wmBlk(40, 8);
    dim3 wmGrd(HH*WW/8);

    // J-side stats (flow-independent)
    jmomD_k<<<lineGrd, lineBlk, 0, stream>>>(y);
    boxW_k<2><<<wGrd, wBlk, 0, stream>>>();            // X -> Y (W)
    boxH2_jstats_k<<<grd4, blk, 0, stream>>>();        // Y -> uJ, Jv (H inline)

    // fin/fout codes: 0 = finit, 1 = g_flowA, 2 = g_flowB
    int fin_code = 0, fout_code = 1;
    for (int t = 1; t <= 5; t++) {
        warp_momD_k<<<wmGrd, wmBlk, 0, stream>>>(x, y, finit, fin_code); // -> X, g_I, g_G
        boxW_k<3><<<wGrd, wBlk, 0, stream>>>();                          // X -> Y (W)
        boxH_fields_k<<<hGrd, blk, 0, stream>>>();                       // Y -> X (H, fields, H)
        boxW_k<3><<<wGrd, wBlk, 0, stream>>>();                          // X -> Y (W)
        double bc1 = 1.0 - pow(0.9, (double)t);
        double bc2 = 1.0 - pow(0.999, (double)t);
        if (t < 5) {
            grad_adam_k<false><<<grd4, blk, 0, stream>>>(y, finit, fin_code, fout_code,
                                                         (float)(1.0/bc1), (float)(1.0/sqrt(bc2)),
                                                         (t == 1) ? 1 : 0);
        } else {
            grad_adam_k<true><<<grd4, blk, 0, stream>>>(y, finit, fin_code, fout_code,
                                                        (float)(1.0/bc1), (float)(1.0/sqrt(bc2)), 0);
        }
        fin_code = fout_code;
        fout_code = (fout_code == 1) ? 2 : 1;
    }

    mse_final_k<<<1, blk, 0, stream>>>(NBLK_FINAL, (float*)d_out);
}